// Round 12
// baseline (152.006 us; speedup 1.0000x reference)
//
#include <hip/hip_runtime.h>
#include <stdint.h>

// ---------------------------------------------------------------------------
// MultiAttentionHead: B=4 S=1024 E=1024 H=16 D=64, fp32 in/out.
// R10: ALL-FP16 single-pass pipeline. R11: batch-balance block remap (minor).
// R12: k_attn Q-TILE 128 -- R11 post-mortem showed per-iter barrier stall ~
// 600 cyc: with a 64-row q-tile the compute window (~350 cyc) was SHORTER
// than the K/V DMA completion (~600-900 cyc L2/LLC), so the dbuf never
// hid the latency. 128 q-rows doubles compute per staged tile (32 MFMA,
// K/V frags register-cached across the two row-groups) and halves total
// staging. LDS 48 KB -> 3 blocks/CU; grid 512.
// Attention: QK = q*k (q pre-scaled 0.125*log2e), static softmax p=exp2(s)
// (f16-rounded for PV; l sums unrounded e), PV = p*v. Rows s >= len[b]:
// uniform attn = mean(V) via vsum (fp32, from projection accumulators).
// Carried: R1 XOR swizzle (0 conflicts), R4 static softmax, R7 dbuf
// (1 barrier/iter), R8 LDS-staged epilogue + direct V^T + fused prep.
// R9 post-mortem: k_proj BK=32 dbuf regressed -> keeps BK=64 2-barrier.
// ---------------------------------------------------------------------------

using u16     = unsigned short;
using half8   = __attribute__((ext_vector_type(8))) _Float16;
using floatx4 = __attribute__((ext_vector_type(4))) float;

#define MFMA16(a, b, c) __builtin_amdgcn_mfma_f32_16x16x32_f16(a, b, c, 0, 0, 0)

__device__ __forceinline__ u16 f2h(float f) {  // f32 -> f16 bits (RTN)
  _Float16 h = (_Float16)f; u16 u; __builtin_memcpy(&u, &h, 2); return u;
}

// DPP rotate within aligned 16-lane rows (pure VALU; no LDS pipe).
template <int CTRL>
__device__ __forceinline__ float dppf(float v) {
  return __int_as_float(__builtin_amdgcn_update_dpp(
      0, __float_as_int(v), CTRL, 0xF, 0xF, true));
}
__device__ __forceinline__ float rowsum16(float v) {  // all-reduce sum, 16 lanes
  v += dppf<0x121>(v);
  v += dppf<0x122>(v);
  v += dppf<0x124>(v);
  v += dppf<0x128>(v);
  return v;
}

// async global->LDS DMA, 16B per lane. LDS dest must be wave-uniform base +
// lane*16 (no per-lane scatter) -- so bank swizzles permute the GLOBAL src.
__device__ __forceinline__ void async_cp16(void* lds, const void* g) {
  __builtin_amdgcn_global_load_lds(
      (__attribute__((address_space(1))) uint32_t*)(uintptr_t)g,
      (__attribute__((address_space(3))) uint32_t*)(uint32_t)(uintptr_t)lds,
      16, 0, 0);
}

// ---------------------------------------------------------------------------
// 1) prep (fused): blocks [0,4096): x -> f16 (block 0 zeroes vsum);
//    blocks [4096,7168): transpose W -> WT[n][k] f16.
// ---------------------------------------------------------------------------
__global__ void k_prep(const float* __restrict__ x, u16* __restrict__ xh,
                       const float* __restrict__ w0, const float* __restrict__ w1,
                       const float* __restrict__ w2,
                       u16* __restrict__ o0, u16* __restrict__ o1,
                       u16* __restrict__ o2, float* __restrict__ vsum) {
  __shared__ float t[32][33];
  const int bx = blockIdx.x;
  if (bx < 4096) {
    int i = (bx * 256 + threadIdx.x) * 4;
    float4 v = *(const float4*)(x + i);
    ushort4 hv;
    hv.x = f2h(v.x);
    hv.y = f2h(v.y);
    hv.z = f2h(v.z);
    hv.w = f2h(v.w);
    *(ushort4*)(xh + i) = hv;
    if (bx == 0) {  // zero vsum (4096 floats) for k_proj's atomics
      float4 z = {0.f, 0.f, 0.f, 0.f};
#pragma unroll
      for (int e = 0; e < 4; e++) ((float4*)vsum)[threadIdx.x * 4 + e] = z;
    }
    return;
  }
  const int id = bx - 4096;                 // 0..3071
  const int z = id >> 10, rem = id & 1023;
  const float* W = z == 0 ? w0 : (z == 1 ? w1 : w2);
  u16* oh = z == 0 ? o0 : (z == 1 ? o1 : o2);
  const int kb = (rem & 31) * 32, nb = (rem >> 5) * 32;
  const int tx = threadIdx.x & 31, ty = threadIdx.x >> 5;
  for (int r = ty; r < 32; r += 8) t[r][tx] = W[(kb + r) * 1024 + nb + tx];
  __syncthreads();
  for (int r = ty; r < 32; r += 8)
    oh[(nb + r) * 1024 + kb + tx] = f2h(t[tx][r]);
}

// ---------------------------------------------------------------------------
// 2) projection GEMM: C[4096][1024] = xh @ Wh + b, fp16 single pass,
//    128x128 tile, BK=64, 2-barrier K-loop (R9: dbuf regresses here).
//    LDS 32 KB staging / 34.8 KB epilogue tile -> 4 blocks/CU. Epilogue
//    stages C through LDS ([128][136]) for 16B stores. z=0/1 -> q/k f16 in
//    [B][H][S][D] (q pre-scaled by 0.125*log2e); z=2 -> V^T f16 + vsum.
// ---------------------------------------------------------------------------
__launch_bounds__(256, 4)
__global__ void k_proj(const u16* __restrict__ xh,
                       const u16* __restrict__ wqT, const u16* __restrict__ wkT,
                       const u16* __restrict__ wvT,
                       const float* __restrict__ bq, const float* __restrict__ bk,
                       const float* __restrict__ bv,
                       u16* __restrict__ qh, u16* __restrict__ kh,
                       u16* __restrict__ vth, float* __restrict__ vsum) {
  __shared__ u16 Sm[17408];  // K-loop: A@0, B@8192 ([128][64] f16 = 16 KB ea);
                             // epilogue: C tile [128][136] (34816 B)
  const int z = blockIdx.z;
  const u16* wT = z == 0 ? wqT : (z == 1 ? wkT : wvT);
  const float* bias = z == 0 ? bq : (z == 1 ? bk : bv);
  u16* oh = z == 0 ? qh : (z == 1 ? kh : vth);
  const float oscale = (z == 0) ? 0.18033688011112042f : 1.0f;  // 0.125*log2(e)

  const int tid = threadIdx.x, l = tid & 63, w = tid >> 6;
  const int quad = l >> 4, col = l & 15;
  const int m0 = blockIdx.x * 128, n0 = blockIdx.y * 128;
  const int wm = (w & 1) * 64, wn = (w >> 1) * 64;

  const int row0 = tid >> 3, ch = tid & 7;
  const int sc8 = (ch ^ (row0 & 7)) * 8;
  int gofs[4], lofs[4];
#pragma unroll
  for (int p = 0; p < 4; p++) {
    gofs[p] = (row0 + 32 * p) * 1024 + sc8;
    lofs[p] = (tid + p * 256) * 8;
  }

  const u16* Ag = xh + m0 * 1024;
  const u16* Bg = wT + n0 * 1024;

  int ar[2][4], br[2][4];
#pragma unroll
  for (int ks = 0; ks < 2; ks++) {
#pragma unroll
    for (int i = 0; i < 4; i++) {
      int r = wm + i * 16 + col;
      ar[ks][i] = r * 64 + (((ks * 4 + quad) ^ (r & 7)) * 8);
    }
#pragma unroll
    for (int j = 0; j < 4; j++) {
      int r = wn + j * 16 + col;
      br[ks][j] = r * 64 + (((ks * 4 + quad) ^ (r & 7)) * 8);
    }
  }

  floatx4 zero4 = {0.f, 0.f, 0.f, 0.f};
  floatx4 acc[4][4];
#pragma unroll
  for (int i = 0; i < 4; i++)
#pragma unroll
    for (int j = 0; j < 4; j++) acc[i][j] = zero4;

  for (int k0 = 0; k0 < 1024; k0 += 64) {
    __syncthreads();  // previous compute done before LDS overwrite
#pragma unroll
    for (int p = 0; p < 4; p++) async_cp16(Sm + lofs[p], Ag + gofs[p] + k0);
#pragma unroll
    for (int p = 0; p < 4; p++)
      async_cp16(Sm + 8192 + lofs[p], Bg + gofs[p] + k0);
    __syncthreads();  // DMA drained

#pragma unroll
    for (int ks = 0; ks < 2; ks++) {
      half8 fa[4], fb[4];
#pragma unroll
      for (int i = 0; i < 4; i++) fa[i] = *(const half8*)(Sm + ar[ks][i]);
#pragma unroll
      for (int j = 0; j < 4; j++)
        fb[j] = *(const half8*)(Sm + 8192 + br[ks][j]);
#pragma unroll
      for (int i = 0; i < 4; i++)
#pragma unroll
        for (int j = 0; j < 4; j++) acc[i][j] = MFMA16(fa[i], fb[j], acc[i][j]);
    }
  }

  // ---- epilogue: stage C tile in LDS ([128][136]) for coalesced stores ----
  const int bidx = m0 >> 10;     // batch index
  const int sbase = m0 & 1023;
  __syncthreads();  // all K-loop LDS reads done before overwrite

#pragma unroll
  for (int j = 0; j < 4; j++) {
    int nloc = wn + j * 16 + col;
    float bb = bias[n0 + nloc];
#pragma unroll
    for (int i = 0; i < 4; i++)
#pragma unroll
      for (int r = 0; r < 4; r++) {
        int mloc = wm + i * 16 + quad * 4 + r;
        Sm[mloc * 136 + nloc] = f2h((acc[i][j][r] + bb) * oscale);
      }
  }
  __syncthreads();

  if (z != 2) {
    // q/k: [bh][s][64] -- row-contiguous 16B chunks
#pragma unroll
    for (int k = 0; k < 8; k++) {
      int c = tid + k * 256;
      int mloc = c >> 4, n = (c & 15) * 8;
      int hh = (n0 + n) >> 6, d = (n0 + n) & 63;
      half8 vv = *(const half8*)(Sm + mloc * 136 + n);
      *(half8*)(oh + ((bidx * 16 + hh) * 1024 + sbase + mloc) * 64 + d) = vv;
    }
  } else {
    // V^T: [bh][d][1024] -- transposed read, s-contiguous 16B stores
#pragma unroll
    for (int k = 0; k < 8; k++) {
      int c = tid + k * 256;
      int nloc = c & 127, s0 = (c >> 7) * 8;
      int hh = (n0 + nloc) >> 6, d = (n0 + nloc) & 63;
      u16 tmp[8];
#pragma unroll
      for (int e = 0; e < 8; e++) tmp[e] = Sm[(s0 + e) * 136 + nloc];
      *(half8*)(vth + ((bidx * 16 + hh) * 64 + d) * 1024 + sbase + s0) =
          *(half8*)tmp;
    }
    // vsum partials from fp32 acc: vsum[bh*64+d] += sum over this block's s
#pragma unroll
    for (int j = 0; j < 4; j++) {
      int nloc = wn + j * 16 + col;
      float bb = bias[n0 + nloc];
      float part = 16.0f * bb;
#pragma unroll
      for (int i = 0; i < 4; i++)
#pragma unroll
        for (int r = 0; r < 4; r++) part += acc[i][j][r];
      part += __shfl_xor(part, 16, 64);  // reduce across quads (same n)
      part += __shfl_xor(part, 32, 64);
      if (quad == 0) {
        int hh = (n0 + nloc) >> 6, d = (n0 + nloc) & 63;
        unsafeAtomicAdd(vsum + (bidx * 16 + hh) * 64 + d, part);
      }
    }
  }
}

// ---------------------------------------------------------------------------
// Swizzled 64x64 f16 tile stage (global -> LDS via DMA).
// ---------------------------------------------------------------------------
__device__ __forceinline__ void stage64(u16* lds, const u16* g, int row_stride,
                                        int tid) {
#pragma unroll
  for (int p = 0; p < 2; p++) {
    int slot = (p * 256 + tid) * 8;  // element index; *2 = bytes
    int row = slot >> 6;
    int gp = (slot >> 3) & 7;
    int gl = gp ^ (row & 7);
    async_cp16(lds + slot, g + row * row_stride + gl * 8);
  }
}

// ---------------------------------------------------------------------------
// 3) flash attention, fp16, static softmax, dbuf, Q-TILE 128 (R12).
//    Block: one (b,h), 128 q-rows (2 groups of 64); t-tiles of 64. Per iter:
//    prefetch tile t+1, K/V frags -> registers ONCE, 32 MFMAs over both row
//    groups, ONE __syncthreads. Compute window (~800 cyc) now exceeds the
//    DMA completion latency, so the barrier no longer stalls (R11 residue).
//    P (f16, [128][64]) aliases Q's LDS (wave-private rows).
//    LDS: QP 16K + 2 x 16K = 48 KB -> 3 blocks/CU. Grid 512, remap spans
//    batches across each CU's resident pair.
// ---------------------------------------------------------------------------
__launch_bounds__(256)
__global__ void k_attn(const u16* __restrict__ qh_g,
                       const u16* __restrict__ kh_g,
                       const u16* __restrict__ vth_g,
                       const float* __restrict__ vsum, const int* __restrict__ elen,
                       float* __restrict__ out) {
  __shared__ u16 QP[8192];        // [128][64] swizzled: Q, then P (aliased)
  __shared__ u16 Bufs[2][8192];   // per buf: K@0, VT@4096 ([64][64] swizzled)
  const int tid = threadIdx.x, l = tid & 63, w = tid >> 6;
  const int quad = l >> 4, col = l & 15;
  // id map: 2b batch (balance-remapped), 4b head, 3b q-tile of 128
  const int id = blockIdx.x;
  const int b = (id + (id >> 8)) & 3;
  const int h = (id >> 2) & 15;
  const int bh = b * 16 + h;
  const int q0 = ((id >> 6) & 7) * 128;
  const int len = elen[b];

  if (q0 >= len) {  // fully-invalid tile: uniform attention over ALL t (ref)
    float val = vsum[bh * 64 + l] * (1.0f / 1024.0f);
    float* op = out + (b * 1024 + q0) * 1024 + h * 64 + l;
    for (int r = w; r < 128; r += 4) op[r * 1024] = val;
    return;
  }

  const u16* kh_b  = kh_g + bh * 65536;
  const u16* vth_b = vth_g + bh * 65536;

  // prologue: stage Q (128 rows = 2 x stage64) + tile 0
  stage64(QP, qh_g + (bh * 1024 + q0) * 64, 64, tid);
  stage64(QP + 4096, qh_g + (bh * 1024 + q0 + 64) * 64, 64, tid);
  stage64(Bufs[0], kh_b, 64, tid);
  stage64(Bufs[0] + 4096, vth_b, 1024, tid);
  __syncthreads();

  half8 qf[2][2];  // [group][ks] persistent Q fragments
  {
    int qrow = w * 16 + col;
    int base = qrow * 64;
#pragma unroll
    for (int ks = 0; ks < 2; ks++) {
      int o = (((ks * 4 + quad) ^ (qrow & 7)) * 8);
      qf[0][ks] = *(const half8*)(QP + base + o);
      qf[1][ks] = *(const half8*)(QP + 4096 + base + o);  // row+64: same &7
    }
  }

  // fragment offsets (same swizzle for K and VT tiles)
  int kvo[2][4];
#pragma unroll
  for (int ks = 0; ks < 2; ks++)
#pragma unroll
    for (int j = 0; j < 4; j++) {
      int n = j * 16 + col;
      kvo[ks][j] = n * 64 + (((ks * 4 + quad) ^ (n & 7)) * 8);
    }
  int p_rd[2];
#pragma unroll
  for (int ks = 0; ks < 2; ks++) {
    int row = w * 16 + col;
    p_rd[ks] = row * 64 + (((ks * 4 + quad) ^ (row & 7)) * 8);
  }
  int p_wr[4][4];
#pragma unroll
  for (int r = 0; r < 4; r++) {
    int row = w * 16 + quad * 4 + r;
#pragma unroll
    for (int j = 0; j < 4; j++) {
      int cj = j * 2 + (col >> 3);
      p_wr[r][j] = row * 64 + ((cj ^ (row & 7)) * 8) + (col & 7);
    }
  }

  floatx4 zero4 = {0.f, 0.f, 0.f, 0.f};
  floatx4 O[2][4];
  float lp[2][4];  // per-thread partial l (reduced after the loop)
#pragma unroll
  for (int g = 0; g < 2; g++) {
#pragma unroll
    for (int j = 0; j < 4; j++) O[g][j] = zero4;
#pragma unroll
    for (int r = 0; r < 4; r++) lp[g][r] = 0.f;
  }

  const int ntt = (len + 63) >> 6;
  for (int tt = 0; tt < ntt; ++tt) {
    const int t0 = tt * 64;
    u16* cur = Bufs[tt & 1];
    if (tt + 1 < ntt) {  // overlap: DMA tile t+1 while computing tile t
      u16* nxt = Bufs[(tt + 1) & 1];
      const int t1 = t0 + 64;
      stage64(nxt, kh_b + t1 * 64, 64, tid);
      stage64(nxt + 4096, vth_b + t1, 1024, tid);
    }

    // ---- K fragments -> registers (read once, used by both groups) ----
    half8 kb[2][4];
#pragma unroll
    for (int ks = 0; ks < 2; ks++)
#pragma unroll
      for (int j = 0; j < 4; j++)
        kb[ks][j] = *(const half8*)(cur + kvo[ks][j]);

    const bool tail = (t0 + 64 > len);
#pragma unroll
    for (int g = 0; g < 2; g++) {
      // ---- raw scores = Q K^T; q carries 0.125*log2e ----
      floatx4 sc[4];
#pragma unroll
      for (int j = 0; j < 4; j++) sc[j] = zero4;
#pragma unroll
      for (int ks = 0; ks < 2; ks++)
#pragma unroll
        for (int j = 0; j < 4; j++)
          sc[j] = MFMA16(qf[g][ks], kb[ks][j], sc[j]);

      if (tail) {  // wave-uniform: only the last partial tile masks
#pragma unroll
        for (int j = 0; j < 4; j++) {
          bool inv = (t0 + j * 16 + col) >= len;
#pragma unroll
          for (int r = 0; r < 4; r++)
            if (inv) sc[j][r] = -3e38f;  // exp2 -> 0
        }
      }

      // ---- static softmax weights: p = exp2(score), f16-rounded for PV ----
#pragma unroll
      for (int r = 0; r < 4; r++) {
#pragma unroll
        for (int j = 0; j < 4; j++) {
          float e = __builtin_exp2f(sc[j][r]);
          QP[g * 4096 + p_wr[r][j]] = f2h(e);  // wave-private rows
          lp[g][r] += e;
        }
      }
    }

    // ---- O += P * V (V frags read once, used by both groups) ----
#pragma unroll
    for (int ks = 0; ks < 2; ks++) {
      half8 vb[4];
#pragma unroll
      for (int j = 0; j < 4; j++)
        vb[j] = *(const half8*)(cur + 4096 + kvo[ks][j]);
      half8 pa0 = *(const half8*)(QP + p_rd[ks]);
      half8 pa1 = *(const half8*)(QP + 4096 + p_rd[ks]);
#pragma unroll
      for (int j = 0; j < 4; j++) {
        O[0][j] = MFMA16(pa0, vb[j], O[0][j]);
        O[1][j] = MFMA16(pa1, vb[j], O[1][j]);
      }
    }

    __syncthreads();  // drain next-tile DMA (overlapped) + sync compute
  }

  // ---- epilogue: reduce l, normalize; per-row override for invalid rows ----
#pragma unroll
  for (int g = 0; g < 2; g++) {
#pragma unroll
    for (int r = 0; r < 4; r++) {
      float l_r = rowsum16(lp[g][r]);
      int s = q0 + g * 64 + w * 16 + quad * 4 + r;
      float invl = 1.0f / l_r;
      bool valid = (s < len);
#pragma unroll
      for (int j = 0; j < 4; j++) {
        int d = j * 16 + col;
        float val = valid ? O[g][j][r] * invl
                          : vsum[bh * 64 + d] * (1.0f / 1024.0f);
        out[(b * 1024 + s) * 1024 + h * 64 + d] = val;
      }
    }
  }
}

// ---------------------------------------------------------------------------
// launch
// ---------------------------------------------------------------------------
extern "C" void kernel_launch(void* const* d_in, const int* in_sizes, int n_in,
                              void* d_out, int out_size, void* d_ws, size_t ws_size,
                              hipStream_t stream) {
  (void)in_sizes; (void)n_in; (void)out_size; (void)ws_size;
  const float* x  = (const float*)d_in[0];
  const float* Wq = (const float*)d_in[1];
  const float* bq = (const float*)d_in[2];
  const float* Wk = (const float*)d_in[3];
  const float* bk = (const float*)d_in[4];
  const float* Wv = (const float*)d_in[5];
  const float* bv = (const float*)d_in[6];
  const int* elen = (const int*)d_in[7];
  float* out = (float*)d_out;

  char* ws = (char*)d_ws;
  const size_t MB = 1024 * 1024;
  u16* xh  = (u16*)(ws + 0 * MB);
  u16* wqT = (u16*)(ws + 8 * MB);
  u16* wkT = (u16*)(ws + 10 * MB);
  u16* wvT = (u16*)(ws + 12 * MB);
  u16* qh  = (u16*)(ws + 14 * MB);
  u16* kh  = (u16*)(ws + 22 * MB);
  u16* vth = (u16*)(ws + 30 * MB);
  float* vsum = (float*)(ws + 38 * MB);  // 4096 floats

  k_prep<<<7168, 256, 0, stream>>>(x, xh, Wq, Wk, Wv, wqT, wkT, wvT, vsum);
  k_proj<<<dim3(32, 8, 3), 256, 0, stream>>>(xh, wqT, wkT, wvT, bq, bk, bv,
                                             qh, kh, vth, vsum);
  k_attn<<<512, 256, 0, stream>>>(qh, kh, vth, vsum, elen, out);
}